// Round 5
// baseline (138.918 us; speedup 1.0000x reference)
//
#include <hip/hip_runtime.h>
#include <hip/hip_bf16.h>
#include <stdint.h>

#define BATCH 4096
#define N_TOT 8192
#define D_DIM 256
#define SHIFT 150.0f
#define SQRT2 1.41421356237309515f

typedef __bf16 bf16_t;
typedef bf16_t bf16x8 __attribute__((ext_vector_type(8)));
typedef bf16_t bf16x4 __attribute__((ext_vector_type(4)));
typedef float f32x4 __attribute__((ext_vector_type(4)));

// Fused: bf16 convert (x sqrt2), positive-pair dot partials, Zrow zero-init.
__global__ void k_prep(const float* __restrict__ hi, const float* __restrict__ hj,
                       bf16_t* __restrict__ hb, float* __restrict__ Zrow,
                       float* __restrict__ posPartial) {
  const int wave = threadIdx.x >> 6, lane = threadIdx.x & 63;
  const int r = blockIdx.x * 4 + wave;
  const size_t off = (size_t)r * D_DIM + lane * 4;
  float4 a = *(const float4*)(hi + off);
  float4 b = *(const float4*)(hj + off);

  bf16x4 oa, ob;
  oa[0] = (bf16_t)(a.x * SQRT2); oa[1] = (bf16_t)(a.y * SQRT2);
  oa[2] = (bf16_t)(a.z * SQRT2); oa[3] = (bf16_t)(a.w * SQRT2);
  ob[0] = (bf16_t)(b.x * SQRT2); ob[1] = (bf16_t)(b.y * SQRT2);
  ob[2] = (bf16_t)(b.z * SQRT2); ob[3] = (bf16_t)(b.w * SQRT2);
  *(bf16x4*)(hb + off) = oa;
  *(bf16x4*)(hb + (size_t)BATCH * D_DIM + off) = ob;

  float d = a.x * b.x + a.y * b.y + a.z * b.z + a.w * b.w;
#pragma unroll
  for (int o = 32; o >= 1; o >>= 1) d += __shfl_xor(d, o);
  __shared__ float ps[4];
  if (lane == 0) ps[wave] = d;
  if (threadIdx.x < 8) Zrow[blockIdx.x * 8 + threadIdx.x] = 0.f;
  __syncthreads();
  if (threadIdx.x == 0) posPartial[blockIdx.x] = ps[0] + ps[1] + ps[2] + ps[3];
}

// Upper-triangular 128x128 tiles of sim = hb.hb^T, register-direct MFMA GEMM:
// no LDS, no barriers. EXPLICIT register double-buffer: frags for step ks+1
// are loaded (source-order) before the MFMAs of step ks, so each wave always
// has 8 loads in flight behind a full MFMA group. launch_bounds(256,3):
// VGPR cap 170 (need ~140: 64 acc + 64 dual-frag) -> 12 waves/CU; 3 waves/SIMD
// x 77cyc MFMA issue covers the ~200cyc L2-hit latency.
__global__ __launch_bounds__(256, 3) void k_gemm(const bf16_t* __restrict__ hb,
                                                 float* __restrict__ Zrow) {
  const int t = blockIdx.x;
  int bj = (int)((sqrtf(8.0f * (float)t + 1.0f) - 1.0f) * 0.5f);
  while ((bj + 1) * (bj + 2) / 2 <= t) ++bj;
  while (bj * (bj + 1) / 2 > t) --bj;
  const int bi = t - bj * (bj + 1) / 2;
  const int rBase = bi * 128;
  const int cBase = bj * 128;
  const bool diag = (bi == bj);

  const int lane = threadIdx.x & 63;
  const int wave = threadIdx.x >> 6;
  const int wm = wave >> 1, wn = wave & 1;
  const int quad = lane >> 4, l16 = lane & 15;

  // per-lane fragment base pointers (row = base + l16, col chunk = quad*8)
  const bf16_t* aptr = hb + (size_t)(rBase + wm * 64 + l16) * D_DIM + quad * 8;
  const bf16_t* bptr = hb + (size_t)(cBase + wn * 64 + l16) * D_DIM + quad * 8;

  f32x4 acc[4][4];
#pragma unroll
  for (int i = 0; i < 4; ++i)
#pragma unroll
    for (int j = 0; j < 4; ++j) acc[i][j] = (f32x4){0.f, 0.f, 0.f, 0.f};

  bf16x8 af[2][4], bfr[2][4];
#pragma unroll
  for (int mt = 0; mt < 4; ++mt) {
    af[0][mt] = *(const bf16x8*)(aptr + (size_t)mt * 16 * D_DIM);
    bfr[0][mt] = *(const bf16x8*)(bptr + (size_t)mt * 16 * D_DIM);
  }

#pragma unroll
  for (int ks = 0; ks < 8; ++ks) {  // K = 8 x 32
    const int cur = ks & 1, nxt = cur ^ 1;
    if (ks < 7) {
#pragma unroll
      for (int mt = 0; mt < 4; ++mt) {
        af[nxt][mt] = *(const bf16x8*)(aptr + (size_t)mt * 16 * D_DIM + (ks + 1) * 32);
        bfr[nxt][mt] = *(const bf16x8*)(bptr + (size_t)mt * 16 * D_DIM + (ks + 1) * 32);
      }
    }
#pragma unroll
    for (int mt = 0; mt < 4; ++mt)
#pragma unroll
      for (int nt = 0; nt < 4; ++nt)
        acc[mt][nt] = __builtin_amdgcn_mfma_f32_16x16x32_bf16(af[cur][mt], bfr[cur][nt],
                                                              acc[mt][nt], 0, 0, 0);
  }

  // epilogue: e = exp(sim - SHIFT); C/D map: col=l16, row=quad*4+reg
  const int rW = rBase + wm * 64 + quad * 4;
  const int cW = cBase + wn * 64 + l16;
  float colAcc[4] = {0.f, 0.f, 0.f, 0.f};
#pragma unroll
  for (int mt = 0; mt < 4; ++mt) {
#pragma unroll
    for (int rg = 0; rg < 4; ++rg) {
      const int rr = rW + mt * 16 + rg;
      float s = 0.f;
#pragma unroll
      for (int nt = 0; nt < 4; ++nt) {
        float e = __expf(acc[mt][nt][rg] - SHIFT);
        if (diag && (rr == cW + nt * 16)) e = 0.f;  // mask self-similarity
        s += e;
        colAcc[nt] += e;
      }
      s += __shfl_xor(s, 1);
      s += __shfl_xor(s, 2);
      s += __shfl_xor(s, 4);
      s += __shfl_xor(s, 8);
      if (l16 == 0) atomicAdd(&Zrow[rr], s);
    }
  }
  if (!diag) {
#pragma unroll
    for (int nt = 0; nt < 4; ++nt) {
      float c = colAcc[nt];
      c += __shfl_xor(c, 16);
      c += __shfl_xor(c, 32);
      if (lane < 16) atomicAdd(&Zrow[cW + nt * 16], c);
    }
  }
}

// One block: loss = mean(log Z + SHIFT) - sum(dot)/2048
__global__ void k_finish(const float* __restrict__ Zrow,
                         const float* __restrict__ posPartial,
                         float* __restrict__ out) {
  const int t = threadIdx.x;  // 0..1023
  float4 z0 = *(const float4*)(Zrow + t * 8);
  float4 z1 = *(const float4*)(Zrow + t * 8 + 4);
  float sl = __logf(z0.x) + __logf(z0.y) + __logf(z0.z) + __logf(z0.w) +
             __logf(z1.x) + __logf(z1.y) + __logf(z1.z) + __logf(z1.w);
  float sp = posPartial[t];
#pragma unroll
  for (int o = 32; o >= 1; o >>= 1) {
    sl += __shfl_xor(sl, o);
    sp += __shfl_xor(sp, o);
  }
  __shared__ float pl[16], pp[16];
  const int wave = t >> 6, lane = t & 63;
  if (lane == 0) { pl[wave] = sl; pp[wave] = sp; }
  __syncthreads();
  if (t == 0) {
    float L = 0.f, P = 0.f;
    for (int i = 0; i < 16; ++i) { L += pl[i]; P += pp[i]; }
    out[0] = L / (float)N_TOT + SHIFT - P / 2048.0f;
  }
}

extern "C" void kernel_launch(void* const* d_in, const int* in_sizes, int n_in,
                              void* d_out, int out_size, void* d_ws, size_t ws_size,
                              hipStream_t stream) {
  const float* hi = (const float*)d_in[0];
  const float* hj = (const float*)d_in[1];
  float* out = (float*)d_out;

  bf16_t* hb = (bf16_t*)d_ws;                                        // 4 MB
  float* Zrow = (float*)((char*)d_ws + (size_t)N_TOT * D_DIM * 2);   // 32 KB
  float* posPartial = Zrow + N_TOT;                                  // 4 KB

  k_prep<<<1024, 256, 0, stream>>>(hi, hj, hb, Zrow, posPartial);
  k_gemm<<<2080, 256, 0, stream>>>(hb, Zrow);
  k_finish<<<1, 1024, 0, stream>>>(Zrow, posPartial, out);
}

// Round 6
// 100.974 us; speedup vs baseline: 1.3758x; 1.3758x over previous
//
#include <hip/hip_runtime.h>
#include <hip/hip_bf16.h>
#include <stdint.h>

#define BATCH 4096
#define N_TOT 8192
#define D_DIM 256
#define SHIFT 150.0f
#define SQRT2 1.41421356237309515f

typedef float f32x4 __attribute__((ext_vector_type(4)));

// global -> LDS direct copy, 16B per lane. LDS dest is wave-uniform base;
// HW scatters lane*16B.
__device__ __forceinline__ void gl_lds16(const void* g, void* l) {
  __builtin_amdgcn_global_load_lds(
      (const __attribute__((address_space(1))) void*)(uintptr_t)g,
      (__attribute__((address_space(3))) void*)(uint32_t)(uintptr_t)l,
      16, 0, 0);
}

// Fused: fp8 e4m3 convert (x sqrt2), positive-pair fp32 dot partials, Zrow init.
// 1024 blocks x 256 threads; wave w of block b owns row r = b*4+w.
__global__ void k_prep(const float* __restrict__ hi, const float* __restrict__ hj,
                       uint8_t* __restrict__ hb8, float* __restrict__ Zrow,
                       float* __restrict__ posPartial) {
  const int wave = threadIdx.x >> 6, lane = threadIdx.x & 63;
  const int r = blockIdx.x * 4 + wave;
  const size_t off = (size_t)r * D_DIM + lane * 4;
  float4 a = *(const float4*)(hi + off);
  float4 b = *(const float4*)(hj + off);

  // pack 4 floats -> 4 fp8 e4m3 bytes (OCP on gfx950), k-ascending
  int wa = __builtin_amdgcn_cvt_pk_fp8_f32(a.x * SQRT2, a.y * SQRT2, 0, false);
  wa = __builtin_amdgcn_cvt_pk_fp8_f32(a.z * SQRT2, a.w * SQRT2, wa, true);
  int wb = __builtin_amdgcn_cvt_pk_fp8_f32(b.x * SQRT2, b.y * SQRT2, 0, false);
  wb = __builtin_amdgcn_cvt_pk_fp8_f32(b.z * SQRT2, b.w * SQRT2, wb, true);
  *(int*)(hb8 + (size_t)r * D_DIM + lane * 4) = wa;
  *(int*)(hb8 + (size_t)(BATCH + r) * D_DIM + lane * 4) = wb;

  float d = a.x * b.x + a.y * b.y + a.z * b.z + a.w * b.w;
#pragma unroll
  for (int o = 32; o >= 1; o >>= 1) d += __shfl_xor(d, o);
  __shared__ float ps[4];
  if (lane == 0) ps[wave] = d;
  if (threadIdx.x < 8) Zrow[blockIdx.x * 8 + threadIdx.x] = 0.f;
  __syncthreads();
  if (threadIdx.x == 0) posPartial[blockIdx.x] = ps[0] + ps[1] + ps[2] + ps[3];
}

// Upper-triangular 128x128 tiles of sim = hb.hb^T in fp8, whole-K staged:
// ONE global_load_lds phase (BK=256 -> 64KB LDS), ONE barrier/drain per block,
// then 8 uninterrupted 16x16x32 fp8 MFMA K-steps. LDS layout: row r, 16B chunk
// slot s holds global chunk s ^ (r&15) (XOR swizzle on the global-source side;
// compatible with global_load_lds's fixed lane*16B scatter). Fragment b64
// reads land <=2-way per bank -> free (m136). exp(sim-SHIFT) fused: row sums
// always, col sums for off-diag tiles (symmetry).
__global__ __launch_bounds__(256, 2) void k_gemm(const uint8_t* __restrict__ hb8,
                                                 float* __restrict__ Zrow) {
  // decode linear block id -> (bi <= bj) triangular pair
  const int t = blockIdx.x;
  int bj = (int)((sqrtf(8.0f * (float)t + 1.0f) - 1.0f) * 0.5f);
  while ((bj + 1) * (bj + 2) / 2 <= t) ++bj;
  while (bj * (bj + 1) / 2 > t) --bj;
  const int bi = t - bj * (bj + 1) / 2;
  const int rBase = bi * 128;
  const int cBase = bj * 128;
  const bool diag = (bi == bj);

  __shared__ __align__(16) uint8_t As[128 * 256];
  __shared__ __align__(16) uint8_t Bs[128 * 256];
  const int lane = threadIdx.x & 63;
  const int wave = threadIdx.x >> 6;

  // staging: waves 0,1 -> As halves; waves 2,3 -> Bs halves. 16 issues x 1KB.
  // Each issue i covers 4 rows; lane = rowOff*16 + c16 writes LDS slot c16 of
  // row (i*4+rowOff), fetching global chunk c16 ^ (row&15).
  {
    const int half = wave & 1;
    const int gbase = (wave < 2 ? rBase : cBase) + half * 64;
    uint8_t* lbase = (wave < 2 ? As : Bs) + half * 64 * 256;
    const int rowOff = lane >> 4, c16 = lane & 15;
#pragma unroll
    for (int i = 0; i < 16; ++i) {
      const int r = i * 4 + rowOff;
      const uint8_t* src = hb8 + (size_t)(gbase + r) * 256 + ((c16 ^ (r & 15)) * 16);
      gl_lds16(src, lbase + i * 1024 + lane * 16);
    }
  }
  __syncthreads();  // the one drain

  const int wm = wave >> 1, wn = wave & 1;
  const int quad = lane >> 4, l16 = lane & 15;

  f32x4 acc[4][4];
#pragma unroll
  for (int i = 0; i < 4; ++i)
#pragma unroll
    for (int j = 0; j < 4; ++j) acc[i][j] = (f32x4){0.f, 0.f, 0.f, 0.f};

#pragma unroll
  for (int ks = 0; ks < 8; ++ks) {  // K = 8 x 32, no barriers inside
    const int j = ks * 4 + quad;                       // 8B chunk index 0..31
    const int off = (((j >> 1) ^ l16) * 16) + (j & 1) * 8;  // un-swizzled byte
    long a[4], b[4];
#pragma unroll
    for (int mt = 0; mt < 4; ++mt)
      a[mt] = *(const long*)(As + (wm * 64 + mt * 16 + l16) * 256 + off);
#pragma unroll
    for (int nt = 0; nt < 4; ++nt)
      b[nt] = *(const long*)(Bs + (wn * 64 + nt * 16 + l16) * 256 + off);
#pragma unroll
    for (int mt = 0; mt < 4; ++mt)
#pragma unroll
      for (int nt = 0; nt < 4; ++nt)
        acc[mt][nt] = __builtin_amdgcn_mfma_f32_16x16x32_fp8_fp8(a[mt], b[nt],
                                                                 acc[mt][nt], 0, 0, 0);
  }

  // epilogue: e = exp(sim - SHIFT); C/D map: col=l16, row=quad*4+reg
  const int rW = rBase + wm * 64 + quad * 4;
  const int cW = cBase + wn * 64 + l16;
  float colAcc[4] = {0.f, 0.f, 0.f, 0.f};
#pragma unroll
  for (int mt = 0; mt < 4; ++mt) {
#pragma unroll
    for (int rg = 0; rg < 4; ++rg) {
      const int rr = rW + mt * 16 + rg;
      float s = 0.f;
#pragma unroll
      for (int nt = 0; nt < 4; ++nt) {
        float e = __expf(acc[mt][nt][rg] - SHIFT);
        if (diag && (rr == cW + nt * 16)) e = 0.f;  // mask self-similarity
        s += e;
        colAcc[nt] += e;
      }
      s += __shfl_xor(s, 1);
      s += __shfl_xor(s, 2);
      s += __shfl_xor(s, 4);
      s += __shfl_xor(s, 8);
      if (l16 == 0) atomicAdd(&Zrow[rr], s);
    }
  }
  if (!diag) {
#pragma unroll
    for (int nt = 0; nt < 4; ++nt) {
      float c = colAcc[nt];
      c += __shfl_xor(c, 16);
      c += __shfl_xor(c, 32);
      if (lane < 16) atomicAdd(&Zrow[cW + nt * 16], c);
    }
  }
}

// One block: loss = mean(log Z + SHIFT) - sum(dot)/2048
__global__ void k_finish(const float* __restrict__ Zrow,
                         const float* __restrict__ posPartial,
                         float* __restrict__ out) {
  const int t = threadIdx.x;  // 0..1023
  float4 z0 = *(const float4*)(Zrow + t * 8);
  float4 z1 = *(const float4*)(Zrow + t * 8 + 4);
  float sl = __logf(z0.x) + __logf(z0.y) + __logf(z0.z) + __logf(z0.w) +
             __logf(z1.x) + __logf(z1.y) + __logf(z1.z) + __logf(z1.w);
  float sp = posPartial[t];
#pragma unroll
  for (int o = 32; o >= 1; o >>= 1) {
    sl += __shfl_xor(sl, o);
    sp += __shfl_xor(sp, o);
  }
  __shared__ float pl[16], pp[16];
  const int wave = t >> 6, lane = t & 63;
  if (lane == 0) { pl[wave] = sl; pp[wave] = sp; }
  __syncthreads();
  if (t == 0) {
    float L = 0.f, P = 0.f;
    for (int i = 0; i < 16; ++i) { L += pl[i]; P += pp[i]; }
    out[0] = L / (float)N_TOT + SHIFT - P / 2048.0f;
  }
}

extern "C" void kernel_launch(void* const* d_in, const int* in_sizes, int n_in,
                              void* d_out, int out_size, void* d_ws, size_t ws_size,
                              hipStream_t stream) {
  const float* hi = (const float*)d_in[0];
  const float* hj = (const float*)d_in[1];
  float* out = (float*)d_out;

  uint8_t* hb8 = (uint8_t*)d_ws;                                   // 2 MB fp8
  float* Zrow = (float*)((char*)d_ws + (size_t)N_TOT * D_DIM);     // 32 KB
  float* posPartial = Zrow + N_TOT;                                // 4 KB

  k_prep<<<1024, 256, 0, stream>>>(hi, hj, hb8, Zrow, posPartial);
  k_gemm<<<2080, 256, 0, stream>>>(hb8, Zrow);
  k_finish<<<1, 1024, 0, stream>>>(Zrow, posPartial, out);
}